// Round 1
// baseline (419.110 us; speedup 1.0000x reference)
//
#include <hip/hip_runtime.h>

#define NNODES 200000
#define NEDGES 3200000
#define NGRAPH 100
#define NPG    2000
#define D      128
#define DOUT   64
#define CAP1   4096     // max distinct layer-1 nodes (expected ~1600)
#define CAP2   8192     // max edges into fetched nodes (expected ~1600)
#define CAPE   65536    // max edges into S1 nodes (expected ~25600)

// ---- init: zero deg/counters/aggregators, -1 the index maps (one dispatch) ----
__global__ void init_kernel(int* deg, int* s2slot, int* s1idx,
                            float* agg1, float* agg2, int* cnt) {
    int n = blockIdx.x * blockDim.x + threadIdx.x;
    if (n < NNODES) { deg[n] = 0; s2slot[n] = -1; s1idx[n] = -1; }
    if (n < CAP1 * D) agg1[n] = 0.0f;
    if (n < NGRAPH * D) agg2[n] = 0.0f;
    if (n < 4) cnt[n] = 0;
}

// ---- mark the 100 fetched nodes (disjoint by construction: node in [i*2000,(i+1)*2000)) ----
__global__ void mark_s2(const int* __restrict__ to_fetch, int* s2slot) {
    int i = threadIdx.x;
    if (i < NGRAPH) s2slot[to_fetch[i] + i * NPG] = i;
}

// ---- pass A: full in-degree + collect edges into fetched nodes + mark S1 candidates ----
__global__ void passA(const int* __restrict__ src, const int* __restrict__ dst,
                      int* deg, const int* __restrict__ s2slot,
                      int* e2src, int* e2slot, int* s1idx, int* cnt) {
    int stride = gridDim.x * blockDim.x;
    for (int e = blockIdx.x * blockDim.x + threadIdx.x; e < NEDGES; e += stride) {
        int d = dst[e];
        atomicAdd(&deg[d], 1);
        int slot = s2slot[d];
        if (slot >= 0) {
            int s = src[e];
            int p = atomicAdd(&cnt[0], 1);
            if (p < CAP2) { e2src[p] = s; e2slot[p] = slot; }
            s1idx[s] = -2;   // benign race: all writers store -2
        }
    }
}

// ---- norm for all nodes + compact S1 candidates into dense indices ----
__global__ void norm_compact(const int* __restrict__ deg, float* norm,
                             int* s1idx, int* s1nodes, int* cnt) {
    int n = blockIdx.x * blockDim.x + threadIdx.x;
    if (n >= NNODES) return;
    norm[n] = rsqrtf(fmaxf((float)deg[n], 1.0f));
    if (s1idx[n] == -2) {
        int p = atomicAdd(&cnt[1], 1);
        if (p < CAP1) { s1nodes[p] = n; s1idx[n] = p; }
        else s1idx[n] = -1;
    }
}

// ---- pass B: collect edges into S1 nodes ----
__global__ void passB(const int* __restrict__ src, const int* __restrict__ dst,
                      const int* __restrict__ s1idx, int* e1src, int* e1j, int* cnt) {
    int stride = gridDim.x * blockDim.x;
    for (int e = blockIdx.x * blockDim.x + threadIdx.x; e < NEDGES; e += stride) {
        int j = s1idx[dst[e]];
        if (j >= 0) {
            int p = atomicAdd(&cnt[2], 1);
            if (p < CAPE) { e1src[p] = src[e]; e1j[p] = j; }
        }
    }
}

// ---- layer-1 aggregation: agg1[j] += features[src]*norm[src], one block per edge ----
__global__ void agg1_kernel(const int* __restrict__ e1src, const int* __restrict__ e1j,
                            const int* __restrict__ cnt,
                            const float* __restrict__ feat, const float* __restrict__ norm,
                            float* agg1) {
    int t = threadIdx.x;                 // 128
    int ne = min(cnt[2], CAPE);
    for (int e = blockIdx.x; e < ne; e += gridDim.x) {
        int s = e1src[e];
        float v = feat[(size_t)s * D + t] * norm[s];
        atomicAdd(&agg1[e1j[e] * D + t], v);
    }
}

// ---- layer-1 GEMM + relu + pre-multiply next-layer norm: h1n = relu((agg1@w1)*norm+b1)*norm ----
__global__ void gemm1(const float* __restrict__ agg1, const float* __restrict__ w1,
                      const float* __restrict__ b1, const float* __restrict__ norm,
                      const int* __restrict__ s1nodes, const int* __restrict__ cnt,
                      float* h1n) {
    int nj = min(cnt[1], CAP1);
    int t = threadIdx.x;                 // 128
    __shared__ float sa[D];
    for (int j = blockIdx.x; j < nj; j += gridDim.x) {
        __syncthreads();
        sa[t] = agg1[j * D + t];
        __syncthreads();
        float acc = 0.0f;
        #pragma unroll
        for (int k = 0; k < D; k++) acc += sa[k] * w1[k * D + t];
        float nm = norm[s1nodes[j]];
        h1n[j * D + t] = fmaxf(acc * nm + b1[t], 0.0f) * nm;
    }
}

// ---- layer-2 aggregation over the ~1600 fetched-node edges ----
__global__ void agg2_kernel(const int* __restrict__ e2src, const int* __restrict__ e2slot,
                            const int* __restrict__ s1idx, const int* __restrict__ cnt,
                            const float* __restrict__ h1n, float* agg2) {
    int t = threadIdx.x;                 // 128
    int ne = min(cnt[0], CAP2);
    for (int e = blockIdx.x; e < ne; e += gridDim.x) {
        int j = s1idx[e2src[e]];
        if (j >= 0) atomicAdd(&agg2[e2slot[e] * D + t], h1n[j * D + t]);
    }
}

// ---- layer-2 GEMM + relu, then out = h2 @ w3^T + b3 ----
__global__ void final_kernel(const float* __restrict__ agg2, const float* __restrict__ w2,
                             const float* __restrict__ b2, const float* __restrict__ norm,
                             const int* __restrict__ to_fetch,
                             const float* __restrict__ w3, const float* __restrict__ b3,
                             float* out) {
    int i = blockIdx.x;                  // 0..99
    int t = threadIdx.x;                 // 128
    __shared__ float sa[D], h2[D];
    sa[t] = agg2[i * D + t];
    __syncthreads();
    float acc = 0.0f;
    #pragma unroll
    for (int k = 0; k < D; k++) acc += sa[k] * w2[k * D + t];
    float nm = norm[to_fetch[i] + i * NPG];
    h2[t] = fmaxf(acc * nm + b2[t], 0.0f);
    __syncthreads();
    if (t < DOUT) {
        float o = 0.0f;
        #pragma unroll
        for (int k = 0; k < D; k++) o += h2[k] * w3[t * D + k];
        out[i * DOUT + t] = o + b3[t];
    }
}

extern "C" void kernel_launch(void* const* d_in, const int* in_sizes, int n_in,
                              void* d_out, int out_size, void* d_ws, size_t ws_size,
                              hipStream_t stream) {
    const float* feat     = (const float*)d_in[0];
    const int*   src      = (const int*)  d_in[1];
    const int*   dst      = (const int*)  d_in[2];
    const int*   to_fetch = (const int*)  d_in[3];
    const float* w1       = (const float*)d_in[4];
    const float* b1       = (const float*)d_in[5];
    const float* w2       = (const float*)d_in[6];
    const float* b2       = (const float*)d_in[7];
    const float* w3       = (const float*)d_in[8];
    const float* b3       = (const float*)d_in[9];
    float* out = (float*)d_out;

    // workspace layout (all 4-byte aligned)
    char* p = (char*)d_ws;
    int*   deg     = (int*)p;            p += (size_t)NNODES * 4;
    float* norm    = (float*)p;          p += (size_t)NNODES * 4;
    int*   s2slot  = (int*)p;            p += (size_t)NNODES * 4;
    int*   s1idx   = (int*)p;            p += (size_t)NNODES * 4;
    int*   s1nodes = (int*)p;            p += (size_t)CAP1 * 4;
    int*   e2src   = (int*)p;            p += (size_t)CAP2 * 4;
    int*   e2slot  = (int*)p;            p += (size_t)CAP2 * 4;
    int*   e1src   = (int*)p;            p += (size_t)CAPE * 4;
    int*   e1j     = (int*)p;            p += (size_t)CAPE * 4;
    float* agg1    = (float*)p;          p += (size_t)CAP1 * D * 4;
    float* h1n     = (float*)p;          p += (size_t)CAP1 * D * 4;
    float* agg2    = (float*)p;          p += (size_t)NGRAPH * D * 4;
    int*   cnt     = (int*)p;            p += 16;

    int initN = CAP1 * D;                // 524288 >= NNODES
    init_kernel<<<(initN + 255) / 256, 256, 0, stream>>>(deg, s2slot, s1idx, agg1, agg2, cnt);
    mark_s2<<<1, 128, 0, stream>>>(to_fetch, s2slot);
    passA<<<4096, 256, 0, stream>>>(src, dst, deg, s2slot, e2src, e2slot, s1idx, cnt);
    norm_compact<<<(NNODES + 255) / 256, 256, 0, stream>>>(deg, norm, s1idx, s1nodes, cnt);
    passB<<<4096, 256, 0, stream>>>(src, dst, s1idx, e1src, e1j, cnt);
    agg1_kernel<<<8192, 128, 0, stream>>>(e1src, e1j, cnt, feat, norm, agg1);
    gemm1<<<CAP1, 128, 0, stream>>>(agg1, w1, b1, norm, s1nodes, cnt, h1n);
    agg2_kernel<<<1024, 128, 0, stream>>>(e2src, e2slot, s1idx, cnt, h1n, agg2);
    final_kernel<<<NGRAPH, 128, 0, stream>>>(agg2, w2, b2, norm, to_fetch, w3, b3, out);
}

// Round 2
// 222.463 us; speedup vs baseline: 1.8840x; 1.8840x over previous
//
#include <hip/hip_runtime.h>

#define NNODES 200000
#define NEDGES 3200000
#define NGRAPH 100
#define NPG    2000
#define D      128
#define DOUT   64
#define CAP1   4096     // max distinct layer-1 nodes (expected ~1600)
#define CAP2   8192     // max edges into fetched nodes (expected ~1600)
#define CAPE   65536    // max edges into S1 nodes (expected ~25600)
#define FBUF   1024     // per-block LDS compaction buffer

// ---- init: zero deg/counters/aggregators, -1 the index maps (one dispatch) ----
__global__ void init_kernel(int* deg, int* s2slot, int* s1idx,
                            float* agg1, float* agg2, int* cnt) {
    int n = blockIdx.x * blockDim.x + threadIdx.x;
    if (n < NNODES) { deg[n] = 0; s2slot[n] = -1; s1idx[n] = -1; }
    if (n < CAP1 * D) agg1[n] = 0.0f;
    if (n < NGRAPH * D) agg2[n] = 0.0f;
    if (n < 4) cnt[n] = 0;
}

// ---- mark the 100 fetched nodes (disjoint: node i lives in [i*2000,(i+1)*2000)) ----
__global__ void mark_s2(const int* __restrict__ to_fetch, int* s2slot) {
    int i = threadIdx.x;
    if (i < NGRAPH) s2slot[to_fetch[i] + i * NPG] = i;
}

// ---- pass A: in-degree + collect edges into fetched nodes (LDS-compacted) + mark S1 ----
__global__ void passA(const int* __restrict__ src, const int* __restrict__ dst,
                      int* deg, const int* __restrict__ s2slot,
                      int* e2src, int* e2slot, int* s1idx, int* cnt) {
    __shared__ int lcnt, lbase;
    __shared__ int bufs[FBUF], bufj[FBUF];
    int tid = threadIdx.x;
    if (tid == 0) lcnt = 0;
    __syncthreads();
    int stride = gridDim.x * blockDim.x;
    int iters = (NEDGES + stride - 1) / stride;
    int e0 = blockIdx.x * blockDim.x + tid;
    for (int it = 0; it < iters; ++it) {
        int e = e0 + it * stride;
        if (e < NEDGES) {
            int d = dst[e];
            atomicAdd(&deg[d], 1);
            int slot = s2slot[d];
            if (slot >= 0) {
                int s = src[e];
                s1idx[s] = -2;             // benign race: all writers store -2
                int p = atomicAdd(&lcnt, 1);
                if (p < FBUF) { bufs[p] = s; bufj[p] = slot; }
            }
        }
        __syncthreads();
        if (lcnt > FBUF - 256) {           // overflow-safety flush (uniform branch)
            int n = min(lcnt, FBUF);
            if (tid == 0) lbase = atomicAdd(&cnt[0], n);
            __syncthreads();
            for (int k = tid; k < n; k += blockDim.x) {
                int g = lbase + k;
                if (g < CAP2) { e2src[g] = bufs[k]; e2slot[g] = bufj[k]; }
            }
            __syncthreads();
            if (tid == 0) lcnt = 0;
            __syncthreads();
        }
    }
    int n = min(lcnt, FBUF);
    if (n > 0) {
        if (tid == 0) lbase = atomicAdd(&cnt[0], n);
        __syncthreads();
        for (int k = tid; k < n; k += blockDim.x) {
            int g = lbase + k;
            if (g < CAP2) { e2src[g] = bufs[k]; e2slot[g] = bufj[k]; }
        }
    }
}

// ---- norm for all nodes + compact S1 candidates (LDS-compacted) ----
__global__ void norm_compact(const int* __restrict__ deg, float* norm,
                             int* s1idx, int* s1nodes, int* cnt) {
    __shared__ int lcnt, lbase;
    __shared__ int buf[FBUF];
    int tid = threadIdx.x;
    if (tid == 0) lcnt = 0;
    __syncthreads();
    int stride = gridDim.x * blockDim.x;
    int iters = (NNODES + stride - 1) / stride;
    int n0 = blockIdx.x * blockDim.x + tid;
    for (int it = 0; it < iters; ++it) {
        int n = n0 + it * stride;
        if (n < NNODES) {
            norm[n] = rsqrtf(fmaxf((float)deg[n], 1.0f));
            if (s1idx[n] == -2) {
                int p = atomicAdd(&lcnt, 1);
                if (p < FBUF) buf[p] = n;
            }
        }
        __syncthreads();
        if (lcnt > FBUF - 256) {
            int cnt_l = min(lcnt, FBUF);
            if (tid == 0) lbase = atomicAdd(&cnt[1], cnt_l);
            __syncthreads();
            for (int k = tid; k < cnt_l; k += blockDim.x) {
                int g = lbase + k; int node = buf[k];
                if (g < CAP1) { s1nodes[g] = node; s1idx[node] = g; }
                else s1idx[node] = -1;
            }
            __syncthreads();
            if (tid == 0) lcnt = 0;
            __syncthreads();
        }
    }
    int cnt_l = min(lcnt, FBUF);
    if (cnt_l > 0) {
        if (tid == 0) lbase = atomicAdd(&cnt[1], cnt_l);
        __syncthreads();
        for (int k = tid; k < cnt_l; k += blockDim.x) {
            int g = lbase + k; int node = buf[k];
            if (g < CAP1) { s1nodes[g] = node; s1idx[node] = g; }
            else s1idx[node] = -1;
        }
    }
}

// ---- pass B: collect edges into S1 nodes (LDS-compacted) ----
__global__ void passB(const int* __restrict__ src, const int* __restrict__ dst,
                      const int* __restrict__ s1idx, int* e1src, int* e1j, int* cnt) {
    __shared__ int lcnt, lbase;
    __shared__ int bufs[FBUF], bufj[FBUF];
    int tid = threadIdx.x;
    if (tid == 0) lcnt = 0;
    __syncthreads();
    int stride = gridDim.x * blockDim.x;
    int iters = (NEDGES + stride - 1) / stride;
    int e0 = blockIdx.x * blockDim.x + tid;
    for (int it = 0; it < iters; ++it) {
        int e = e0 + it * stride;
        if (e < NEDGES) {
            int j = s1idx[dst[e]];
            if (j >= 0) {
                int p = atomicAdd(&lcnt, 1);
                if (p < FBUF) { bufs[p] = src[e]; bufj[p] = j; }
            }
        }
        __syncthreads();
        if (lcnt > FBUF - 256) {
            int n = min(lcnt, FBUF);
            if (tid == 0) lbase = atomicAdd(&cnt[2], n);
            __syncthreads();
            for (int k = tid; k < n; k += blockDim.x) {
                int g = lbase + k;
                if (g < CAPE) { e1src[g] = bufs[k]; e1j[g] = bufj[k]; }
            }
            __syncthreads();
            if (tid == 0) lcnt = 0;
            __syncthreads();
        }
    }
    int n = min(lcnt, FBUF);
    if (n > 0) {
        if (tid == 0) lbase = atomicAdd(&cnt[2], n);
        __syncthreads();
        for (int k = tid; k < n; k += blockDim.x) {
            int g = lbase + k;
            if (g < CAPE) { e1src[g] = bufs[k]; e1j[g] = bufj[k]; }
        }
    }
}

// ---- layer-1 aggregation: agg1[j] += features[src]*norm[src] ----
__global__ void agg1_kernel(const int* __restrict__ e1src, const int* __restrict__ e1j,
                            const int* __restrict__ cnt,
                            const float* __restrict__ feat, const float* __restrict__ norm,
                            float* agg1) {
    int t = threadIdx.x;                 // 128
    int ne = min(cnt[2], CAPE);
    for (int e = blockIdx.x; e < ne; e += gridDim.x) {
        int s = e1src[e];
        float v = feat[(size_t)s * D + t] * norm[s];
        atomicAdd(&agg1[e1j[e] * D + t], v);
    }
}

// ---- layer-1 GEMM + relu + pre-multiply next-layer norm ----
__global__ void gemm1(const float* __restrict__ agg1, const float* __restrict__ w1,
                      const float* __restrict__ b1, const float* __restrict__ norm,
                      const int* __restrict__ s1nodes, const int* __restrict__ cnt,
                      float* h1n) {
    int nj = min(cnt[1], CAP1);
    int t = threadIdx.x;                 // 128
    __shared__ float sa[D];
    for (int j = blockIdx.x; j < nj; j += gridDim.x) {
        __syncthreads();
        sa[t] = agg1[j * D + t];
        __syncthreads();
        float acc = 0.0f;
        #pragma unroll
        for (int k = 0; k < D; k++) acc += sa[k] * w1[k * D + t];
        float nm = norm[s1nodes[j]];
        h1n[j * D + t] = fmaxf(acc * nm + b1[t], 0.0f) * nm;
    }
}

// ---- layer-2 aggregation over the ~1600 fetched-node edges ----
__global__ void agg2_kernel(const int* __restrict__ e2src, const int* __restrict__ e2slot,
                            const int* __restrict__ s1idx, const int* __restrict__ cnt,
                            const float* __restrict__ h1n, float* agg2) {
    int t = threadIdx.x;                 // 128
    int ne = min(cnt[0], CAP2);
    for (int e = blockIdx.x; e < ne; e += gridDim.x) {
        int j = s1idx[e2src[e]];
        if (j >= 0) atomicAdd(&agg2[e2slot[e] * D + t], h1n[j * D + t]);
    }
}

// ---- layer-2 GEMM + relu, then out = h2 @ w3^T + b3 ----
__global__ void final_kernel(const float* __restrict__ agg2, const float* __restrict__ w2,
                             const float* __restrict__ b2, const float* __restrict__ norm,
                             const int* __restrict__ to_fetch,
                             const float* __restrict__ w3, const float* __restrict__ b3,
                             float* out) {
    int i = blockIdx.x;                  // 0..99
    int t = threadIdx.x;                 // 128
    __shared__ float sa[D], h2[D];
    sa[t] = agg2[i * D + t];
    __syncthreads();
    float acc = 0.0f;
    #pragma unroll
    for (int k = 0; k < D; k++) acc += sa[k] * w2[k * D + t];
    float nm = norm[to_fetch[i] + i * NPG];
    h2[t] = fmaxf(acc * nm + b2[t], 0.0f);
    __syncthreads();
    if (t < DOUT) {
        float o = 0.0f;
        #pragma unroll
        for (int k = 0; k < D; k++) o += h2[k] * w3[t * D + k];
        out[i * DOUT + t] = o + b3[t];
    }
}

extern "C" void kernel_launch(void* const* d_in, const int* in_sizes, int n_in,
                              void* d_out, int out_size, void* d_ws, size_t ws_size,
                              hipStream_t stream) {
    const float* feat     = (const float*)d_in[0];
    const int*   src      = (const int*)  d_in[1];
    const int*   dst      = (const int*)  d_in[2];
    const int*   to_fetch = (const int*)  d_in[3];
    const float* w1       = (const float*)d_in[4];
    const float* b1       = (const float*)d_in[5];
    const float* w2       = (const float*)d_in[6];
    const float* b2       = (const float*)d_in[7];
    const float* w3       = (const float*)d_in[8];
    const float* b3       = (const float*)d_in[9];
    float* out = (float*)d_out;

    // workspace layout (all 4-byte aligned)
    char* p = (char*)d_ws;
    int*   deg     = (int*)p;            p += (size_t)NNODES * 4;
    float* norm    = (float*)p;          p += (size_t)NNODES * 4;
    int*   s2slot  = (int*)p;            p += (size_t)NNODES * 4;
    int*   s1idx   = (int*)p;            p += (size_t)NNODES * 4;
    int*   s1nodes = (int*)p;            p += (size_t)CAP1 * 4;
    int*   e2src   = (int*)p;            p += (size_t)CAP2 * 4;
    int*   e2slot  = (int*)p;            p += (size_t)CAP2 * 4;
    int*   e1src   = (int*)p;            p += (size_t)CAPE * 4;
    int*   e1j     = (int*)p;            p += (size_t)CAPE * 4;
    float* agg1    = (float*)p;          p += (size_t)CAP1 * D * 4;
    float* h1n     = (float*)p;          p += (size_t)CAP1 * D * 4;
    float* agg2    = (float*)p;          p += (size_t)NGRAPH * D * 4;
    int*   cnt     = (int*)p;            p += 16;

    int initN = CAP1 * D;                // 524288 >= NNODES
    init_kernel<<<(initN + 255) / 256, 256, 0, stream>>>(deg, s2slot, s1idx, agg1, agg2, cnt);
    mark_s2<<<1, 128, 0, stream>>>(to_fetch, s2slot);
    passA<<<2048, 256, 0, stream>>>(src, dst, deg, s2slot, e2src, e2slot, s1idx, cnt);
    norm_compact<<<512, 256, 0, stream>>>(deg, norm, s1idx, s1nodes, cnt);
    passB<<<2048, 256, 0, stream>>>(src, dst, s1idx, e1src, e1j, cnt);
    agg1_kernel<<<2048, 128, 0, stream>>>(e1src, e1j, cnt, feat, norm, agg1);
    gemm1<<<CAP1, 128, 0, stream>>>(agg1, w1, b1, norm, s1nodes, cnt, h1n);
    agg2_kernel<<<1024, 128, 0, stream>>>(e2src, e2slot, s1idx, cnt, h1n, agg2);
    final_kernel<<<NGRAPH, 128, 0, stream>>>(agg2, w2, b2, norm, to_fetch, w3, b3, out);
}

// Round 3
// 127.998 us; speedup vs baseline: 3.2743x; 1.7380x over previous
//
#include <hip/hip_runtime.h>

#define NNODES 200000
#define NEDGES 3200000
#define NGRAPH 100
#define NPG    2000
#define D      128
#define DOUT   64
#define CAP1   4096     // max distinct layer-1 nodes (expected ~1600)
#define CAP2   8192     // max edges into fetched nodes (expected ~1600)
#define CAPE   65536    // max edges into S1 nodes (expected ~25600)
#define FBUF   2048     // per-block LDS compaction buffer

// ---- init: zero deg/need/counters/aggregators, -1 the s1 index map ----
__global__ void init_kernel(int* deg, int* s1idx, unsigned char* need,
                            float* agg1, float* agg2, int* cnt) {
    int n = blockIdx.x * blockDim.x + threadIdx.x;
    if (n < NNODES) { deg[n] = 0; s1idx[n] = -1; need[n] = 0; }
    if (n < CAP1 * D) agg1[n] = 0.0f;
    if (n < NGRAPH * D) agg2[n] = 0.0f;
    if (n < 4) cnt[n] = 0;
}

// ---- pass A: find edges into fetched nodes (membership by arithmetic),
//      collect (src,slot), mark S1 sources. No degree atomics. ----
__global__ void passA2(const int* __restrict__ src, const int4* __restrict__ dst4,
                       const int* __restrict__ to_fetch,
                       int* e2src, int* e2slot, int* s1idx, int* cnt) {
    __shared__ int tf[NGRAPH];
    __shared__ int lcnt, lbase;
    __shared__ int bufs[FBUF], bufj[FBUF];
    int tid = threadIdx.x;
    for (int i = tid; i < NGRAPH; i += blockDim.x) tf[i] = to_fetch[i];
    if (tid == 0) lcnt = 0;
    __syncthreads();
    const int NV = NEDGES / 4;
    int stride = gridDim.x * blockDim.x;
    int iters = (NV + stride - 1) / stride;
    int v0 = blockIdx.x * blockDim.x + tid;
    for (int it = 0; it < iters; ++it) {
        int v = v0 + it * stride;
        if (v < NV) {
            int4 d4 = dst4[v];
            int ds[4] = {d4.x, d4.y, d4.z, d4.w};
            #pragma unroll
            for (int q = 0; q < 4; ++q) {
                int d = ds[q];
                int slot = d / NPG;                  // magic-mul division
                if (tf[slot] == d - slot * NPG) {
                    int s = src[v * 4 + q];
                    s1idx[s] = -2;                   // benign race: all write -2
                    int p = atomicAdd(&lcnt, 1);
                    if (p < FBUF) { bufs[p] = s; bufj[p] = slot; }
                }
            }
        }
        __syncthreads();
        if (lcnt > FBUF - 1024) {                    // safety flush (uniform)
            int n = min(lcnt, FBUF);
            if (tid == 0) lbase = atomicAdd(&cnt[0], n);
            __syncthreads();
            for (int k = tid; k < n; k += blockDim.x) {
                int g = lbase + k;
                if (g < CAP2) { e2src[g] = bufs[k]; e2slot[g] = bufj[k]; }
            }
            __syncthreads();
            if (tid == 0) lcnt = 0;
            __syncthreads();
        }
    }
    int n = min(lcnt, FBUF);
    if (n > 0) {
        if (tid == 0) lbase = atomicAdd(&cnt[0], n);
        __syncthreads();
        for (int k = tid; k < n; k += blockDim.x) {
            int g = lbase + k;
            if (g < CAP2) { e2src[g] = bufs[k]; e2slot[g] = bufj[k]; }
        }
    }
}

// ---- compact S1 candidates into dense indices; set need flags for S1 + fetched ----
__global__ void compact1(int* s1idx, int* s1nodes, unsigned char* need,
                         const int* __restrict__ to_fetch, int* cnt) {
    __shared__ int lcnt, lbase;
    __shared__ int buf[FBUF];
    int tid = threadIdx.x;
    if (blockIdx.x == 0 && tid < NGRAPH) need[to_fetch[tid] + tid * NPG] = 1;
    if (tid == 0) lcnt = 0;
    __syncthreads();
    int stride = gridDim.x * blockDim.x;
    int iters = (NNODES + stride - 1) / stride;
    int n0 = blockIdx.x * blockDim.x + tid;
    for (int it = 0; it < iters; ++it) {
        int n = n0 + it * stride;
        if (n < NNODES && s1idx[n] == -2) {
            int p = atomicAdd(&lcnt, 1);
            if (p < FBUF) buf[p] = n;
        }
        __syncthreads();
        if (lcnt > FBUF - 256) {
            int c = min(lcnt, FBUF);
            if (tid == 0) lbase = atomicAdd(&cnt[1], c);
            __syncthreads();
            for (int k = tid; k < c; k += blockDim.x) {
                int g = lbase + k; int node = buf[k];
                if (g < CAP1) { s1nodes[g] = node; s1idx[node] = g; need[node] = 1; }
                else s1idx[node] = -1;
            }
            __syncthreads();
            if (tid == 0) lcnt = 0;
            __syncthreads();
        }
    }
    int c = min(lcnt, FBUF);
    if (c > 0) {
        if (tid == 0) lbase = atomicAdd(&cnt[1], c);
        __syncthreads();
        for (int k = tid; k < c; k += blockDim.x) {
            int g = lbase + k; int node = buf[k];
            if (g < CAP1) { s1nodes[g] = node; s1idx[node] = g; need[node] = 1; }
            else s1idx[node] = -1;
        }
    }
}

// ---- pass B: collect edges into S1 nodes; flag their sources as needed ----
__global__ void passB2(const int* __restrict__ src, const int4* __restrict__ dst4,
                       const int* __restrict__ s1idx, unsigned char* need,
                       int* e1src, int* e1j, int* cnt) {
    __shared__ int lcnt, lbase;
    __shared__ int bufs[FBUF], bufj[FBUF];
    int tid = threadIdx.x;
    if (tid == 0) lcnt = 0;
    __syncthreads();
    const int NV = NEDGES / 4;
    int stride = gridDim.x * blockDim.x;
    int iters = (NV + stride - 1) / stride;
    int v0 = blockIdx.x * blockDim.x + tid;
    for (int it = 0; it < iters; ++it) {
        int v = v0 + it * stride;
        if (v < NV) {
            int4 d4 = dst4[v];
            int ds[4] = {d4.x, d4.y, d4.z, d4.w};
            #pragma unroll
            for (int q = 0; q < 4; ++q) {
                int j = s1idx[ds[q]];
                if (j >= 0) {
                    int s = src[v * 4 + q];
                    need[s] = 1;                     // benign race
                    int p = atomicAdd(&lcnt, 1);
                    if (p < FBUF) { bufs[p] = s; bufj[p] = j; }
                }
            }
        }
        __syncthreads();
        if (lcnt > FBUF - 1024) {
            int n = min(lcnt, FBUF);
            if (tid == 0) lbase = atomicAdd(&cnt[2], n);
            __syncthreads();
            for (int k = tid; k < n; k += blockDim.x) {
                int g = lbase + k;
                if (g < CAPE) { e1src[g] = bufs[k]; e1j[g] = bufj[k]; }
            }
            __syncthreads();
            if (tid == 0) lcnt = 0;
            __syncthreads();
        }
    }
    int n = min(lcnt, FBUF);
    if (n > 0) {
        if (tid == 0) lbase = atomicAdd(&cnt[2], n);
        __syncthreads();
        for (int k = tid; k < n; k += blockDim.x) {
            int g = lbase + k;
            if (g < CAPE) { e1src[g] = bufs[k]; e1j[g] = bufj[k]; }
        }
    }
}

// ---- pass C: degree count, only for needed nodes (~27K of 200K) ----
__global__ void passC(const int4* __restrict__ dst4, const unsigned char* __restrict__ need,
                      int* deg) {
    const int NV = NEDGES / 4;
    int stride = gridDim.x * blockDim.x;
    for (int v = blockIdx.x * blockDim.x + threadIdx.x; v < NV; v += stride) {
        int4 d4 = dst4[v];
        int ds[4] = {d4.x, d4.y, d4.z, d4.w};
        #pragma unroll
        for (int q = 0; q < 4; ++q)
            if (need[ds[q]]) atomicAdd(&deg[ds[q]], 1);
    }
}

// ---- layer-1 aggregation: agg1[j] += features[src]*rsqrt(max(deg[src],1)) ----
__global__ void agg1_kernel(const int* __restrict__ e1src, const int* __restrict__ e1j,
                            const int* __restrict__ cnt, const int* __restrict__ deg,
                            const float* __restrict__ feat, float* agg1) {
    int t = threadIdx.x;                 // 128
    int ne = min(cnt[2], CAPE);
    for (int e = blockIdx.x; e < ne; e += gridDim.x) {
        int s = e1src[e];
        float nm = rsqrtf(fmaxf((float)deg[s], 1.0f));
        float v = feat[(size_t)s * D + t] * nm;
        atomicAdd(&agg1[e1j[e] * D + t], v);
    }
}

// ---- layer-1 GEMM + relu + pre-multiply next-layer norm ----
__global__ void gemm1(const float* __restrict__ agg1, const float* __restrict__ w1,
                      const float* __restrict__ b1, const int* __restrict__ deg,
                      const int* __restrict__ s1nodes, const int* __restrict__ cnt,
                      float* h1n) {
    int nj = min(cnt[1], CAP1);
    int t = threadIdx.x;                 // 128
    __shared__ float sa[D];
    for (int j = blockIdx.x; j < nj; j += gridDim.x) {
        __syncthreads();
        sa[t] = agg1[j * D + t];
        __syncthreads();
        float acc = 0.0f;
        #pragma unroll
        for (int k = 0; k < D; k++) acc += sa[k] * w1[k * D + t];
        float nm = rsqrtf(fmaxf((float)deg[s1nodes[j]], 1.0f));
        h1n[j * D + t] = fmaxf(acc * nm + b1[t], 0.0f) * nm;
    }
}

// ---- layer-2 aggregation over the ~1600 fetched-node edges ----
__global__ void agg2_kernel(const int* __restrict__ e2src, const int* __restrict__ e2slot,
                            const int* __restrict__ s1idx, const int* __restrict__ cnt,
                            const float* __restrict__ h1n, float* agg2) {
    int t = threadIdx.x;                 // 128
    int ne = min(cnt[0], CAP2);
    for (int e = blockIdx.x; e < ne; e += gridDim.x) {
        int j = s1idx[e2src[e]];
        if (j >= 0) atomicAdd(&agg2[e2slot[e] * D + t], h1n[j * D + t]);
    }
}

// ---- layer-2 GEMM + relu, then out = h2 @ w3^T + b3 ----
__global__ void final_kernel(const float* __restrict__ agg2, const float* __restrict__ w2,
                             const float* __restrict__ b2, const int* __restrict__ deg,
                             const int* __restrict__ to_fetch,
                             const float* __restrict__ w3, const float* __restrict__ b3,
                             float* out) {
    int i = blockIdx.x;                  // 0..99
    int t = threadIdx.x;                 // 128
    __shared__ float sa[D], h2[D];
    sa[t] = agg2[i * D + t];
    __syncthreads();
    float acc = 0.0f;
    #pragma unroll
    for (int k = 0; k < D; k++) acc += sa[k] * w2[k * D + t];
    float nm = rsqrtf(fmaxf((float)deg[to_fetch[i] + i * NPG], 1.0f));
    h2[t] = fmaxf(acc * nm + b2[t], 0.0f);
    __syncthreads();
    if (t < DOUT) {
        float o = 0.0f;
        #pragma unroll
        for (int k = 0; k < D; k++) o += h2[k] * w3[t * D + k];
        out[i * DOUT + t] = o + b3[t];
    }
}

extern "C" void kernel_launch(void* const* d_in, const int* in_sizes, int n_in,
                              void* d_out, int out_size, void* d_ws, size_t ws_size,
                              hipStream_t stream) {
    const float* feat     = (const float*)d_in[0];
    const int*   src      = (const int*)  d_in[1];
    const int*   dst      = (const int*)  d_in[2];
    const int*   to_fetch = (const int*)  d_in[3];
    const float* w1       = (const float*)d_in[4];
    const float* b1       = (const float*)d_in[5];
    const float* w2       = (const float*)d_in[6];
    const float* b2       = (const float*)d_in[7];
    const float* w3       = (const float*)d_in[8];
    const float* b3       = (const float*)d_in[9];
    float* out = (float*)d_out;
    const int4* dst4 = (const int4*)dst;

    // workspace layout
    char* p = (char*)d_ws;
    int*   deg     = (int*)p;            p += (size_t)NNODES * 4;
    int*   s1idx   = (int*)p;            p += (size_t)NNODES * 4;
    int*   s1nodes = (int*)p;            p += (size_t)CAP1 * 4;
    int*   e2src   = (int*)p;            p += (size_t)CAP2 * 4;
    int*   e2slot  = (int*)p;            p += (size_t)CAP2 * 4;
    int*   e1src   = (int*)p;            p += (size_t)CAPE * 4;
    int*   e1j     = (int*)p;            p += (size_t)CAPE * 4;
    float* agg1    = (float*)p;          p += (size_t)CAP1 * D * 4;
    float* h1n     = (float*)p;          p += (size_t)CAP1 * D * 4;
    float* agg2    = (float*)p;          p += (size_t)NGRAPH * D * 4;
    int*   cnt     = (int*)p;            p += 16;
    unsigned char* need = (unsigned char*)p; p += (size_t)NNODES;

    int initN = CAP1 * D;                // 524288 >= NNODES
    init_kernel<<<(initN + 255) / 256, 256, 0, stream>>>(deg, s1idx, need, agg1, agg2, cnt);
    passA2<<<2048, 256, 0, stream>>>(src, dst4, to_fetch, e2src, e2slot, s1idx, cnt);
    compact1<<<512, 256, 0, stream>>>(s1idx, s1nodes, need, to_fetch, cnt);
    passB2<<<2048, 256, 0, stream>>>(src, dst4, s1idx, need, e1src, e1j, cnt);
    passC<<<2048, 256, 0, stream>>>(dst4, need, deg);
    agg1_kernel<<<2048, 128, 0, stream>>>(e1src, e1j, cnt, deg, feat, agg1);
    gemm1<<<CAP1, 128, 0, stream>>>(agg1, w1, b1, deg, s1nodes, cnt, h1n);
    agg2_kernel<<<1024, 128, 0, stream>>>(e2src, e2slot, s1idx, cnt, h1n, agg2);
    final_kernel<<<NGRAPH, 128, 0, stream>>>(agg2, w2, b2, deg, to_fetch, w3, b3, out);
}